// Round 2
// baseline (400.026 us; speedup 1.0000x reference)
//
#include <hip/hip_runtime.h>

#define B_ 128
#define T_ 2048
#define H_ 128

typedef __attribute__((ext_vector_type(8))) short short8;
typedef __attribute__((ext_vector_type(4))) float f32x4;

__device__ __forceinline__ unsigned short f2b(float f) {
    unsigned int u = __float_as_uint(f);
    u += 0x7fffu + ((u >> 16) & 1u);   // RNE
    return (unsigned short)(u >> 16);
}
__device__ __forceinline__ short8 pack8(const float4 x, const float4 y) {
    short8 r;
    r[0] = (short)f2b(x.x); r[1] = (short)f2b(x.y);
    r[2] = (short)f2b(x.z); r[3] = (short)f2b(x.w);
    r[4] = (short)f2b(y.x); r[5] = (short)f2b(y.y);
    r[6] = (short)f2b(y.z); r[7] = (short)f2b(y.w);
    return r;
}
__device__ __forceinline__ float tanh_fast(float x) {
    x = fminf(fmaxf(x, -20.f), 20.f);
    float e = __expf(2.f * x);
    return (e - 1.f) / (e + 1.f);
}

// ---------------- Phase 1: energy[b,t] = W_a . tanh(W_h hp + W_d hd) + b_a ----
// GEMM rows = b*T+t (M=262144), N=128, K=256 (hp|hd). fp32 in, bf16 MFMA.
// v2: depth-8 cross-tile register pipeline for A (16 float4 in flight);
//     W stored in LDS in exact read order [kt][nt][lane]*16B -> conflict-free
//     ds_read_b128 with a single address VGPR + immediate offsets.
__global__ __launch_bounds__(512) void energy_kernel(
    const float* __restrict__ Hp,
    const float* __restrict__ Hd,
    const float* __restrict__ Wh,
    const float* __restrict__ Wd,
    const float* __restrict__ Wa,
    const float* __restrict__ ba_p,
    float* __restrict__ energy,
    int ntiles)   // tiles of 128 rows
{
    __shared__ unsigned short Wpack[8 * 8 * 64 * 8];   // [kt][nt][lane][8] bf16 = 64 KB
    __shared__ float Was[H_];                          // 512 B

    const int tid = threadIdx.x;

    // stage W_h (kt 0..3) and W_d (kt 4..7), fp32 [o][h] -> read-order bf16 LDS.
    // element W[o][h]: kt=h>>5, nt=o>>4, lane=((h>>3)&3)*16 + (o&15), elem=h&7
    for (int i = tid; i < (H_ * H_) / 4; i += 512) {
        int o  = i >> 5;           // 32 float4 per row
        int c4 = i & 31;
        float4 wh = *(const float4*)&Wh[o * H_ + c4 * 4];
        float4 wd = *(const float4*)&Wd[o * H_ + c4 * 4];
        uint2 ph, pdv;
        ph.x  = (unsigned)f2b(wh.x) | ((unsigned)f2b(wh.y) << 16);
        ph.y  = (unsigned)f2b(wh.z) | ((unsigned)f2b(wh.w) << 16);
        pdv.x = (unsigned)f2b(wd.x) | ((unsigned)f2b(wd.y) << 16);
        pdv.y = (unsigned)f2b(wd.z) | ((unsigned)f2b(wd.w) << 16);
        int nt   = o >> 4;
        int l15  = o & 15;
        int kth  = c4 >> 3;          // h>>5
        int lq   = (c4 >> 1) & 3;    // (h>>3)&3
        int half = (c4 & 1) * 4;     // h&7 base within octet
        int bh = ((kth * 8 + nt) * 64 + lq * 16 + l15) * 8 + half;
        int bd = (((kth + 4) * 8 + nt) * 64 + lq * 16 + l15) * 8 + half;
        *(uint2*)&Wpack[bh] = ph;
        *(uint2*)&Wpack[bd] = pdv;
    }
    if (tid < H_) Was[tid] = Wa[tid];
    __syncthreads();

    const float ba = ba_p[0];

    const int wave = tid >> 6;     // 0..7
    const int lane = tid & 63;
    const int l15  = lane & 15;
    const int lq   = lane >> 4;    // 0..3

    const unsigned short* wb = Wpack + lane * 8;   // one LDS addr VGPR for ALL reads

    const size_t estep = (size_t)gridDim.x * 128 * H_;   // element stride per tile-step

    const int row0 = blockIdx.x * 128 + wave * 16;
    const float* pp = Hp + (size_t)(row0 + l15) * H_ + lq * 8;
    const float* pd = Hd + (size_t)(row0 + l15) * H_ + lq * 8;

    // prologue: load all 8 K-chunks (16 float4) of the first tile
    float4 abuf[16];
    #pragma unroll
    for (int kt = 0; kt < 8; kt++) {
        const float* s = (kt < 4) ? (pp + kt * 32) : (pd + (kt - 4) * 32);
        abuf[2 * kt]     = *(const float4*)s;
        abuf[2 * kt + 1] = *(const float4*)(s + 4);
    }

    for (int tile = blockIdx.x; tile < ntiles; tile += gridDim.x) {
        const int row_base = tile * 128 + wave * 16;
        // advance to next tile (0 on last iteration: harmless re-load, L3-hot)
        const size_t adv = (tile + (int)gridDim.x < ntiles) ? estep : 0;
        pp += adv; pd += adv;

        f32x4 acc[8];
        #pragma unroll
        for (int nt = 0; nt < 8; nt++) acc[nt] = (f32x4){0.f, 0.f, 0.f, 0.f};

        #pragma unroll
        for (int kt = 0; kt < 8; kt++) {
            short8 af = pack8(abuf[2 * kt], abuf[2 * kt + 1]);
            // refill this slot with NEXT tile's chunk (depth-8 pipeline)
            const float* s = (kt < 4) ? (pp + kt * 32) : (pd + (kt - 4) * 32);
            abuf[2 * kt]     = *(const float4*)s;
            abuf[2 * kt + 1] = *(const float4*)(s + 4);
            #pragma unroll
            for (int nt = 0; nt < 8; nt++) {
                short8 bf = *(const short8*)(wb + kt * 4096 + nt * 512);
                acc[nt] = __builtin_amdgcn_mfma_f32_16x16x32_bf16(af, bf, acc[nt], 0, 0, 0);
            }
        }

        float ep[4] = {0.f, 0.f, 0.f, 0.f};
        #pragma unroll
        for (int nt = 0; nt < 8; nt++) {
            const float wa = Was[nt * 16 + l15];
            #pragma unroll
            for (int r = 0; r < 4; r++) ep[r] += tanh_fast(acc[nt][r]) * wa;
        }
        #pragma unroll
        for (int m = 1; m < 16; m <<= 1) {
            #pragma unroll
            for (int r = 0; r < 4; r++) ep[r] += __shfl_xor(ep[r], m, 64);
        }
        if (l15 == 0) {
            // C/D: col = lane&15, row = lq*4 + r
            #pragma unroll
            for (int r = 0; r < 4; r++)
                energy[row_base + lq * 4 + r] = ep[r] + ba;
        }
    }
}

// ---------------- Phase 2: fused softmax + partial context ----------------
// grid = B*8; block (b, sl) recomputes the softmax reductions from energy/accw
// (redundant, deterministic, L2-resident) then handles t in [sl*256, sl*256+256):
// writes its alpha slice and accumulates its context partial.
__global__ __launch_bounds__(256) void softmax_ctx_kernel(
    const float* __restrict__ Hp,
    const float* __restrict__ accw,
    const float* __restrict__ beta_p,
    const float* __restrict__ energy,
    float* __restrict__ out_alpha,
    float* __restrict__ cpart)   // [B][8][H]
{
    __shared__ float al_s[T_];      // 8 KB
    __shared__ float red[8 * H_];   // 4 KB
    __shared__ float sred[8];

    const int sl   = blockIdx.x & 7;
    const int b    = blockIdx.x >> 3;
    const int tid  = threadIdx.x;
    const int lane = tid & 63;
    const int wid  = tid >> 6;   // 0..3

    const float beta_pos = log1pf(__expf(beta_p[0]));

    // ---- load energy & acc_w for all T (8 per thread, vectorized) ----
    float av[8], ev[8];
    {
        const float* pa = accw + b * T_ + tid * 8;
        const float* pe = energy + b * T_ + tid * 8;
        float4 a0 = *(const float4*)pa, a1 = *(const float4*)(pa + 4);
        float4 e0 = *(const float4*)pe, e1 = *(const float4*)(pe + 4);
        av[0]=a0.x; av[1]=a0.y; av[2]=a0.z; av[3]=a0.w;
        av[4]=a1.x; av[5]=a1.y; av[6]=a1.z; av[7]=a1.w;
        ev[0]=e0.x; ev[1]=e0.y; ev[2]=e0.z; ev[3]=e0.w;
        ev[4]=e1.x; ev[5]=e1.y; ev[6]=e1.z; ev[7]=e1.w;
    }
    float amax = -1e30f;
    #pragma unroll
    for (int i = 0; i < 8; i++) amax = fmaxf(amax, av[i]);
    for (int m = 32; m >= 1; m >>= 1) amax = fmaxf(amax, __shfl_xor(amax, m, 64));
    if (lane == 0) sred[wid] = amax;
    __syncthreads();
    if (tid == 0)
        sred[4] = fmaxf(fmaxf(sred[0], sred[1]), fmaxf(sred[2], sred[3]));
    __syncthreads();
    const float invd = beta_pos / fmaxf(sred[4], 1e-6f);

    float sv[8], smax = -1e30f;
    #pragma unroll
    for (int i = 0; i < 8; i++) {
        sv[i] = ev[i] * (1.f + av[i] * invd);
        smax = fmaxf(smax, sv[i]);
    }
    for (int m = 32; m >= 1; m >>= 1) smax = fmaxf(smax, __shfl_xor(smax, m, 64));
    __syncthreads();
    if (lane == 0) sred[wid] = smax;
    __syncthreads();
    if (tid == 0)
        sred[5] = fmaxf(fmaxf(sred[0], sred[1]), fmaxf(sred[2], sred[3]));
    __syncthreads();
    const float smax_all = sred[5];

    float p[8], psum = 0.f;
    #pragma unroll
    for (int i = 0; i < 8; i++) { p[i] = __expf(sv[i] - smax_all); psum += p[i]; }
    for (int m = 32; m >= 1; m >>= 1) psum += __shfl_xor(psum, m, 64);
    __syncthreads();
    if (lane == 0) sred[wid] = psum;
    __syncthreads();
    if (tid == 0)
        sred[6] = sred[0] + sred[1] + sred[2] + sred[3];
    __syncthreads();
    const float invS = 1.f / sred[6];

    #pragma unroll
    for (int i = 0; i < 8; i++) al_s[tid * 8 + i] = p[i] * invS;
    __syncthreads();

    // write this block's alpha slice (coalesced, each t written by exactly one block)
    out_alpha[b * T_ + sl * 256 + tid] = al_s[sl * 256 + tid];

    // ---- context partial over rows t in [sl*256, sl*256+256) ----
    const int row = tid >> 5;      // 0..7
    const int c4  = tid & 31;      // float4 index within the 128-float row

    float c0 = 0.f, c1 = 0.f, c2 = 0.f, c3 = 0.f;
    const float* base = Hp + ((size_t)b * T_ + sl * 256) * H_ + c4 * 4;
    const float* al   = al_s + sl * 256;
    #pragma unroll 4
    for (int it = 0; it < 32; it++) {
        int t = it * 8 + row;
        float a = al[t];
        float4 v = *(const float4*)(base + (size_t)t * H_);
        c0 += a * v.x; c1 += a * v.y; c2 += a * v.z; c3 += a * v.w;
    }
    red[row * H_ + c4 * 4 + 0] = c0;
    red[row * H_ + c4 * 4 + 1] = c1;
    red[row * H_ + c4 * 4 + 2] = c2;
    red[row * H_ + c4 * 4 + 3] = c3;
    __syncthreads();
    if (tid < H_) {
        float s = 0.f;
        #pragma unroll
        for (int g = 0; g < 8; g++) s += red[g * H_ + tid];
        cpart[(b * 8 + sl) * H_ + tid] = s;
    }
}

__global__ __launch_bounds__(256) void ctx_reduce_kernel(
    const float* __restrict__ cpart, float* __restrict__ out_ctx)
{
    int i = blockIdx.x * 256 + threadIdx.x;   // i < B*H
    if (i < B_ * H_) {
        int b = i >> 7, h = i & 127;
        float s = 0.f;
        #pragma unroll
        for (int g = 0; g < 8; g++) s += cpart[(b * 8 + g) * H_ + h];
        out_ctx[i] = s;
    }
}

extern "C" void kernel_launch(void* const* d_in, const int* in_sizes, int n_in,
                              void* d_out, int out_size, void* d_ws, size_t ws_size,
                              hipStream_t stream) {
    const float* Hp   = (const float*)d_in[0];
    const float* Hd   = (const float*)d_in[1];
    const float* accw = (const float*)d_in[2];
    const float* Wh   = (const float*)d_in[3];
    const float* Wd   = (const float*)d_in[4];
    const float* Wa   = (const float*)d_in[5];
    const float* ba   = (const float*)d_in[6];
    const float* beta = (const float*)d_in[7];

    float* energy_ws = (float*)d_ws;                 // B*T fp32 = 1 MB
    float* cpart_ws  = energy_ws + B_ * T_;          // B*8*H fp32 = 512 KB

    float* out_ctx   = (float*)d_out;                // [B,H]
    float* out_alpha = out_ctx + B_ * H_;            // [B,T]

    const int ntiles = (B_ * T_) / 128;   // 2048 tiles of 128 rows
    energy_kernel<<<512, 512, 0, stream>>>(Hp, Hd, Wh, Wd, Wa, ba, energy_ws, ntiles);
    softmax_ctx_kernel<<<B_ * 8, 256, 0, stream>>>(Hp, accw, beta, energy_ws, out_alpha, cpart_ws);
    ctx_reduce_kernel<<<(B_ * H_ + 255) / 256, 256, 0, stream>>>(cpart_ws, out_ctx);
}

// Round 3
// 399.876 us; speedup vs baseline: 1.0004x; 1.0004x over previous
//
#include <hip/hip_runtime.h>

#define B_ 128
#define T_ 2048
#define H_ 128

typedef __attribute__((ext_vector_type(8))) short short8;
typedef __attribute__((ext_vector_type(4))) float f32x4;

__device__ __forceinline__ unsigned short f2b(float f) {
    unsigned int u = __float_as_uint(f);
    u += 0x7fffu + ((u >> 16) & 1u);   // RNE
    return (unsigned short)(u >> 16);
}
__device__ __forceinline__ short8 pack8(const float4 x, const float4 y) {
    short8 r;
    r[0] = (short)f2b(x.x); r[1] = (short)f2b(x.y);
    r[2] = (short)f2b(x.z); r[3] = (short)f2b(x.w);
    r[4] = (short)f2b(y.x); r[5] = (short)f2b(y.y);
    r[6] = (short)f2b(y.z); r[7] = (short)f2b(y.w);
    return r;
}
__device__ __forceinline__ float tanh_fast(float x) {
    x = fminf(fmaxf(x, -20.f), 20.f);
    float e = __expf(2.f * x);
    return (e - 1.f) / (e + 1.f);
}

// ---------------- Phase 1: energy[b,t] = W_a . tanh(W_h hp + W_d hd) + b_a ----
// GEMM rows = b*T+t (M=262144), N=128, K=256 (hp|hd). fp32 in, bf16 MFMA.
// v3: depth-4 cross-tile register pipeline (8 float4 in flight = 32 VGPR,
//     fits the 128-VGPR budget at 2 blocks/CU -> no spill, unlike v2's depth-8);
//     W in LDS in exact read order [kt][nt][lane]*16B -> conflict-free
//     ds_read_b128 with one address VGPR + immediate offsets.
__global__ __launch_bounds__(512) void energy_kernel(
    const float* __restrict__ Hp,
    const float* __restrict__ Hd,
    const float* __restrict__ Wh,
    const float* __restrict__ Wd,
    const float* __restrict__ Wa,
    const float* __restrict__ ba_p,
    float* __restrict__ energy,
    int ntiles)   // tiles of 128 rows
{
    __shared__ unsigned short Wpack[8 * 8 * 64 * 8];   // [kt][nt][lane][8] bf16 = 64 KB
    __shared__ float Was[H_];                          // 512 B

    const int tid = threadIdx.x;

    // stage W_h (kt 0..3) and W_d (kt 4..7), fp32 [o][h] -> read-order bf16 LDS.
    // element W[o][h]: kt=h>>5, nt=o>>4, lane=((h>>3)&3)*16 + (o&15), elem=h&7
    for (int i = tid; i < (H_ * H_) / 4; i += 512) {
        int o  = i >> 5;           // 32 float4 per row
        int c4 = i & 31;
        float4 wh = *(const float4*)&Wh[o * H_ + c4 * 4];
        float4 wd = *(const float4*)&Wd[o * H_ + c4 * 4];
        uint2 ph, pdv;
        ph.x  = (unsigned)f2b(wh.x) | ((unsigned)f2b(wh.y) << 16);
        ph.y  = (unsigned)f2b(wh.z) | ((unsigned)f2b(wh.w) << 16);
        pdv.x = (unsigned)f2b(wd.x) | ((unsigned)f2b(wd.y) << 16);
        pdv.y = (unsigned)f2b(wd.z) | ((unsigned)f2b(wd.w) << 16);
        int nt   = o >> 4;
        int l15  = o & 15;
        int kth  = c4 >> 3;          // h>>5
        int lq   = (c4 >> 1) & 3;    // (h>>3)&3
        int half = (c4 & 1) * 4;     // h&7 base within octet
        int bh = ((kth * 8 + nt) * 64 + lq * 16 + l15) * 8 + half;
        int bd = (((kth + 4) * 8 + nt) * 64 + lq * 16 + l15) * 8 + half;
        *(uint2*)&Wpack[bh] = ph;
        *(uint2*)&Wpack[bd] = pdv;
    }
    if (tid < H_) Was[tid] = Wa[tid];
    __syncthreads();

    const float ba = ba_p[0];

    const int wave = tid >> 6;     // 0..7
    const int lane = tid & 63;
    const int l15  = lane & 15;
    const int lq   = lane >> 4;    // 0..3

    const unsigned short* wb = Wpack + lane * 8;   // one LDS addr VGPR for ALL reads

    const size_t estep = (size_t)gridDim.x * 128 * H_;   // element stride per tile-step

    const int row0 = blockIdx.x * 128 + wave * 16;
    const float* pp = Hp + (size_t)(row0 + l15) * H_ + lq * 8;
    const float* pd = Hd + (size_t)(row0 + l15) * H_ + lq * 8;

    // prologue: load Hp chunks 0..3 (K-chunks 0..3) of the first tile
    float4 abuf[8];
    #pragma unroll
    for (int c = 0; c < 4; c++) {
        abuf[2 * c]     = *(const float4*)(pp + c * 32);
        abuf[2 * c + 1] = *(const float4*)(pp + c * 32 + 4);
    }

    for (int tile = blockIdx.x; tile < ntiles; tile += gridDim.x) {
        const int row_base = tile * 128 + wave * 16;
        // advance for next tile (0 on last iteration: harmless in-bounds re-load)
        const size_t adv = (tile + (int)gridDim.x < ntiles) ? estep : 0;
        const float* ppn = pp + adv;

        f32x4 acc[8];
        #pragma unroll
        for (int nt = 0; nt < 8; nt++) acc[nt] = (f32x4){0.f, 0.f, 0.f, 0.f};

        // steady state: slot kt&3 consumed at kt, refilled with data needed at kt+4.
        //   kt 0..3: consume Hp chunk kt,   issue Hd chunk kt   (K-chunk kt+4)
        //   kt 4..7: consume Hd chunk kt-4, issue next tile's Hp chunk kt-4
        #pragma unroll
        for (int kt = 0; kt < 8; kt++) {
            const int sl = kt & 3;
            short8 af = pack8(abuf[2 * sl], abuf[2 * sl + 1]);
            const float* s = (kt < 4) ? (pd + kt * 32) : (ppn + (kt - 4) * 32);
            abuf[2 * sl]     = *(const float4*)s;
            abuf[2 * sl + 1] = *(const float4*)(s + 4);
            #pragma unroll
            for (int nt = 0; nt < 8; nt++) {
                short8 bf = *(const short8*)(wb + kt * 4096 + nt * 512);
                acc[nt] = __builtin_amdgcn_mfma_f32_16x16x32_bf16(af, bf, acc[nt], 0, 0, 0);
            }
        }
        pp = ppn;
        pd += adv;

        float ep[4] = {0.f, 0.f, 0.f, 0.f};
        #pragma unroll
        for (int nt = 0; nt < 8; nt++) {
            const float wa = Was[nt * 16 + l15];
            #pragma unroll
            for (int r = 0; r < 4; r++) ep[r] += tanh_fast(acc[nt][r]) * wa;
        }
        #pragma unroll
        for (int m = 1; m < 16; m <<= 1) {
            #pragma unroll
            for (int r = 0; r < 4; r++) ep[r] += __shfl_xor(ep[r], m, 64);
        }
        if (l15 == 0) {
            // C/D: col = lane&15, row = lq*4 + r
            #pragma unroll
            for (int r = 0; r < 4; r++)
                energy[row_base + lq * 4 + r] = ep[r] + ba;
        }
    }
}

// ---------------- Phase 2: fused softmax + partial context ----------------
// grid = B*8; block (b, sl) recomputes the softmax reductions from energy/accw
// (redundant, deterministic, L2-resident) then handles t in [sl*256, sl*256+256):
// writes its alpha slice and accumulates its context partial.
__global__ __launch_bounds__(256) void softmax_ctx_kernel(
    const float* __restrict__ Hp,
    const float* __restrict__ accw,
    const float* __restrict__ beta_p,
    const float* __restrict__ energy,
    float* __restrict__ out_alpha,
    float* __restrict__ cpart)   // [B][8][H]
{
    __shared__ float al_s[T_];      // 8 KB
    __shared__ float red[8 * H_];   // 4 KB
    __shared__ float sred[8];

    const int sl   = blockIdx.x & 7;
    const int b    = blockIdx.x >> 3;
    const int tid  = threadIdx.x;
    const int lane = tid & 63;
    const int wid  = tid >> 6;   // 0..3

    const float beta_pos = log1pf(__expf(beta_p[0]));

    // ---- load energy & acc_w for all T (8 per thread, vectorized) ----
    float av[8], ev[8];
    {
        const float* pa = accw + b * T_ + tid * 8;
        const float* pe = energy + b * T_ + tid * 8;
        float4 a0 = *(const float4*)pa, a1 = *(const float4*)(pa + 4);
        float4 e0 = *(const float4*)pe, e1 = *(const float4*)(pe + 4);
        av[0]=a0.x; av[1]=a0.y; av[2]=a0.z; av[3]=a0.w;
        av[4]=a1.x; av[5]=a1.y; av[6]=a1.z; av[7]=a1.w;
        ev[0]=e0.x; ev[1]=e0.y; ev[2]=e0.z; ev[3]=e0.w;
        ev[4]=e1.x; ev[5]=e1.y; ev[6]=e1.z; ev[7]=e1.w;
    }
    float amax = -1e30f;
    #pragma unroll
    for (int i = 0; i < 8; i++) amax = fmaxf(amax, av[i]);
    for (int m = 32; m >= 1; m >>= 1) amax = fmaxf(amax, __shfl_xor(amax, m, 64));
    if (lane == 0) sred[wid] = amax;
    __syncthreads();
    if (tid == 0)
        sred[4] = fmaxf(fmaxf(sred[0], sred[1]), fmaxf(sred[2], sred[3]));
    __syncthreads();
    const float invd = beta_pos / fmaxf(sred[4], 1e-6f);

    float sv[8], smax = -1e30f;
    #pragma unroll
    for (int i = 0; i < 8; i++) {
        sv[i] = ev[i] * (1.f + av[i] * invd);
        smax = fmaxf(smax, sv[i]);
    }
    for (int m = 32; m >= 1; m >>= 1) smax = fmaxf(smax, __shfl_xor(smax, m, 64));
    __syncthreads();
    if (lane == 0) sred[wid] = smax;
    __syncthreads();
    if (tid == 0)
        sred[5] = fmaxf(fmaxf(sred[0], sred[1]), fmaxf(sred[2], sred[3]));
    __syncthreads();
    const float smax_all = sred[5];

    float p[8], psum = 0.f;
    #pragma unroll
    for (int i = 0; i < 8; i++) { p[i] = __expf(sv[i] - smax_all); psum += p[i]; }
    for (int m = 32; m >= 1; m >>= 1) psum += __shfl_xor(psum, m, 64);
    __syncthreads();
    if (lane == 0) sred[wid] = psum;
    __syncthreads();
    if (tid == 0)
        sred[6] = sred[0] + sred[1] + sred[2] + sred[3];
    __syncthreads();
    const float invS = 1.f / sred[6];

    #pragma unroll
    for (int i = 0; i < 8; i++) al_s[tid * 8 + i] = p[i] * invS;
    __syncthreads();

    // write this block's alpha slice (coalesced, each t written by exactly one block)
    out_alpha[b * T_ + sl * 256 + tid] = al_s[sl * 256 + tid];

    // ---- context partial over rows t in [sl*256, sl*256+256) ----
    const int row = tid >> 5;      // 0..7
    const int c4  = tid & 31;      // float4 index within the 128-float row

    float c0 = 0.f, c1 = 0.f, c2 = 0.f, c3 = 0.f;
    const float* base = Hp + ((size_t)b * T_ + sl * 256) * H_ + c4 * 4;
    const float* al   = al_s + sl * 256;
    #pragma unroll 4
    for (int it = 0; it < 32; it++) {
        int t = it * 8 + row;
        float a = al[t];
        float4 v = *(const float4*)(base + (size_t)t * H_);
        c0 += a * v.x; c1 += a * v.y; c2 += a * v.z; c3 += a * v.w;
    }
    red[row * H_ + c4 * 4 + 0] = c0;
    red[row * H_ + c4 * 4 + 1] = c1;
    red[row * H_ + c4 * 4 + 2] = c2;
    red[row * H_ + c4 * 4 + 3] = c3;
    __syncthreads();
    if (tid < H_) {
        float s = 0.f;
        #pragma unroll
        for (int g = 0; g < 8; g++) s += red[g * H_ + tid];
        cpart[(b * 8 + sl) * H_ + tid] = s;
    }
}

__global__ __launch_bounds__(256) void ctx_reduce_kernel(
    const float* __restrict__ cpart, float* __restrict__ out_ctx)
{
    int i = blockIdx.x * 256 + threadIdx.x;   // i < B*H
    if (i < B_ * H_) {
        int b = i >> 7, h = i & 127;
        float s = 0.f;
        #pragma unroll
        for (int g = 0; g < 8; g++) s += cpart[(b * 8 + g) * H_ + h];
        out_ctx[i] = s;
    }
}

extern "C" void kernel_launch(void* const* d_in, const int* in_sizes, int n_in,
                              void* d_out, int out_size, void* d_ws, size_t ws_size,
                              hipStream_t stream) {
    const float* Hp   = (const float*)d_in[0];
    const float* Hd   = (const float*)d_in[1];
    const float* accw = (const float*)d_in[2];
    const float* Wh   = (const float*)d_in[3];
    const float* Wd   = (const float*)d_in[4];
    const float* Wa   = (const float*)d_in[5];
    const float* ba   = (const float*)d_in[6];
    const float* beta = (const float*)d_in[7];

    float* energy_ws = (float*)d_ws;                 // B*T fp32 = 1 MB
    float* cpart_ws  = energy_ws + B_ * T_;          // B*8*H fp32 = 512 KB

    float* out_ctx   = (float*)d_out;                // [B,H]
    float* out_alpha = out_ctx + B_ * H_;            // [B,T]

    const int ntiles = (B_ * T_) / 128;   // 2048 tiles of 128 rows
    energy_kernel<<<512, 512, 0, stream>>>(Hp, Hd, Wh, Wd, Wa, ba, energy_ws, ntiles);
    softmax_ctx_kernel<<<B_ * 8, 256, 0, stream>>>(Hp, accw, beta, energy_ws, out_alpha, cpart_ws);
    ctx_reduce_kernel<<<(B_ * H_ + 255) / 256, 256, 0, stream>>>(cpart_ws, out_ctx);
}

// Round 4
// 324.467 us; speedup vs baseline: 1.2329x; 1.2324x over previous
//
#include <hip/hip_runtime.h>

#define B_ 128
#define T_ 2048
#define H_ 128

typedef __attribute__((ext_vector_type(8))) short short8;
typedef __attribute__((ext_vector_type(4))) float f32x4;

__device__ __forceinline__ unsigned short f2b(float f) {
    unsigned int u = __float_as_uint(f);
    u += 0x7fffu + ((u >> 16) & 1u);   // RNE
    return (unsigned short)(u >> 16);
}
__device__ __forceinline__ short8 pack8(const float4 x, const float4 y) {
    short8 r;
    r[0] = (short)f2b(x.x); r[1] = (short)f2b(x.y);
    r[2] = (short)f2b(x.z); r[3] = (short)f2b(x.w);
    r[4] = (short)f2b(y.x); r[5] = (short)f2b(y.y);
    r[6] = (short)f2b(y.z); r[7] = (short)f2b(y.w);
    return r;
}
__device__ __forceinline__ float tanh_fast(float x) {
    x = fminf(fmaxf(x, -20.f), 20.f);
    float e = __expf(2.f * x);
    return (e - 1.f) / (e + 1.f);
}

// ---------------- Phase 1: energy[b,t] = W_a . tanh(W_h hp + W_d hd) + b_a ----
// GEMM rows = b*T+t (M=262144), N=128, K=256 (hp|hd). fp32 in, bf16 MFMA.
// v4: depth-4 cross-tile register pipeline as v3, but with sched_barrier(0)
//     fencing each kt region. v3 spilled (VGPR pegged at 128, 115 MB scratch
//     writes) because the fully-unrolled body let the scheduler hoist all
//     global refills + many ds_reads to the top. The 8 scheduling regions cap
//     in-flight state: 2 global loads issued/region (consumed 4 regions later
//     -> counted vmcnt waits), <=8 ds_read_b128 in flight.
__global__ __launch_bounds__(512) void energy_kernel(
    const float* __restrict__ Hp,
    const float* __restrict__ Hd,
    const float* __restrict__ Wh,
    const float* __restrict__ Wd,
    const float* __restrict__ Wa,
    const float* __restrict__ ba_p,
    float* __restrict__ energy,
    int ntiles)   // tiles of 128 rows
{
    __shared__ unsigned short Wpack[8 * 8 * 64 * 8];   // [kt][nt][lane][8] bf16 = 64 KB
    __shared__ float Was[H_];                          // 512 B

    const int tid = threadIdx.x;

    // stage W_h (kt 0..3) and W_d (kt 4..7), fp32 [o][h] -> read-order bf16 LDS.
    // element W[o][h]: kt=h>>5, nt=o>>4, lane=((h>>3)&3)*16 + (o&15), elem=h&7
    for (int i = tid; i < (H_ * H_) / 4; i += 512) {
        int o  = i >> 5;           // 32 float4 per row
        int c4 = i & 31;
        float4 wh = *(const float4*)&Wh[o * H_ + c4 * 4];
        float4 wd = *(const float4*)&Wd[o * H_ + c4 * 4];
        uint2 ph, pdv;
        ph.x  = (unsigned)f2b(wh.x) | ((unsigned)f2b(wh.y) << 16);
        ph.y  = (unsigned)f2b(wh.z) | ((unsigned)f2b(wh.w) << 16);
        pdv.x = (unsigned)f2b(wd.x) | ((unsigned)f2b(wd.y) << 16);
        pdv.y = (unsigned)f2b(wd.z) | ((unsigned)f2b(wd.w) << 16);
        int nt   = o >> 4;
        int l15  = o & 15;
        int kth  = c4 >> 3;          // h>>5
        int lq   = (c4 >> 1) & 3;    // (h>>3)&3
        int half = (c4 & 1) * 4;     // h&7 base within octet
        int bh = ((kth * 8 + nt) * 64 + lq * 16 + l15) * 8 + half;
        int bd = (((kth + 4) * 8 + nt) * 64 + lq * 16 + l15) * 8 + half;
        *(uint2*)&Wpack[bh] = ph;
        *(uint2*)&Wpack[bd] = pdv;
    }
    if (tid < H_) Was[tid] = Wa[tid];
    __syncthreads();

    const float ba = ba_p[0];

    const int wave = tid >> 6;     // 0..7
    const int lane = tid & 63;
    const int l15  = lane & 15;
    const int lq   = lane >> 4;    // 0..3

    const unsigned short* wb = Wpack + lane * 8;   // one LDS addr VGPR for ALL reads

    const size_t estep = (size_t)gridDim.x * 128 * H_;   // element stride per tile-step

    const int row0 = blockIdx.x * 128 + wave * 16;
    const float* pp = Hp + (size_t)(row0 + l15) * H_ + lq * 8;
    const float* pd = Hd + (size_t)(row0 + l15) * H_ + lq * 8;

    // prologue: load Hp chunks 0..3 (K-chunks 0..3) of the first tile
    float4 abuf[8];
    #pragma unroll
    for (int c = 0; c < 4; c++) {
        abuf[2 * c]     = *(const float4*)(pp + c * 32);
        abuf[2 * c + 1] = *(const float4*)(pp + c * 32 + 4);
    }

    for (int tile = blockIdx.x; tile < ntiles; tile += gridDim.x) {
        const int row_base = tile * 128 + wave * 16;
        // advance for next tile (0 on last iteration: harmless in-bounds re-load)
        const size_t adv = (tile + (int)gridDim.x < ntiles) ? estep : 0;
        const float* ppn = pp + adv;

        f32x4 acc[8];
        #pragma unroll
        for (int nt = 0; nt < 8; nt++) acc[nt] = (f32x4){0.f, 0.f, 0.f, 0.f};

        // steady state: slot kt&3 consumed at kt, refilled with data needed at kt+4.
        //   kt 0..3: consume Hp chunk kt,   issue Hd chunk kt   (K-chunk kt+4)
        //   kt 4..7: consume Hd chunk kt-4, issue next tile's Hp chunk kt-4
        // sched_barrier(0) per region: loads stay put, VGPR pressure capped.
        #pragma unroll
        for (int kt = 0; kt < 8; kt++) {
            const int sl = kt & 3;
            short8 af = pack8(abuf[2 * sl], abuf[2 * sl + 1]);
            const float* s = (kt < 4) ? (pd + kt * 32) : (ppn + (kt - 4) * 32);
            abuf[2 * sl]     = *(const float4*)s;
            abuf[2 * sl + 1] = *(const float4*)(s + 4);
            #pragma unroll
            for (int nt = 0; nt < 8; nt++) {
                short8 bf = *(const short8*)(wb + kt * 4096 + nt * 512);
                acc[nt] = __builtin_amdgcn_mfma_f32_16x16x32_bf16(af, bf, acc[nt], 0, 0, 0);
            }
            __builtin_amdgcn_sched_barrier(0);
        }
        pp = ppn;
        pd += adv;

        float ep[4] = {0.f, 0.f, 0.f, 0.f};
        #pragma unroll
        for (int nt = 0; nt < 8; nt++) {
            const float wa = Was[nt * 16 + l15];
            #pragma unroll
            for (int r = 0; r < 4; r++) ep[r] += tanh_fast(acc[nt][r]) * wa;
        }
        #pragma unroll
        for (int m = 1; m < 16; m <<= 1) {
            #pragma unroll
            for (int r = 0; r < 4; r++) ep[r] += __shfl_xor(ep[r], m, 64);
        }
        if (l15 == 0) {
            // C/D: col = lane&15, row = lq*4 + r
            #pragma unroll
            for (int r = 0; r < 4; r++)
                energy[row_base + lq * 4 + r] = ep[r] + ba;
        }
    }
}

// ---------------- Phase 2: fused softmax + partial context ----------------
// grid = B*8; block (b, sl) recomputes the softmax reductions from energy/accw
// (redundant, deterministic, L2-resident) then handles t in [sl*256, sl*256+256):
// writes its alpha slice and accumulates its context partial.
__global__ __launch_bounds__(256) void softmax_ctx_kernel(
    const float* __restrict__ Hp,
    const float* __restrict__ accw,
    const float* __restrict__ beta_p,
    const float* __restrict__ energy,
    float* __restrict__ out_alpha,
    float* __restrict__ cpart)   // [B][8][H]
{
    __shared__ float al_s[T_];      // 8 KB
    __shared__ float red[8 * H_];   // 4 KB
    __shared__ float sred[8];

    const int sl   = blockIdx.x & 7;
    const int b    = blockIdx.x >> 3;
    const int tid  = threadIdx.x;
    const int lane = tid & 63;
    const int wid  = tid >> 6;   // 0..3

    const float beta_pos = log1pf(__expf(beta_p[0]));

    // ---- load energy & acc_w for all T (8 per thread, vectorized) ----
    float av[8], ev[8];
    {
        const float* pa = accw + b * T_ + tid * 8;
        const float* pe = energy + b * T_ + tid * 8;
        float4 a0 = *(const float4*)pa, a1 = *(const float4*)(pa + 4);
        float4 e0 = *(const float4*)pe, e1 = *(const float4*)(pe + 4);
        av[0]=a0.x; av[1]=a0.y; av[2]=a0.z; av[3]=a0.w;
        av[4]=a1.x; av[5]=a1.y; av[6]=a1.z; av[7]=a1.w;
        ev[0]=e0.x; ev[1]=e0.y; ev[2]=e0.z; ev[3]=e0.w;
        ev[4]=e1.x; ev[5]=e1.y; ev[6]=e1.z; ev[7]=e1.w;
    }
    float amax = -1e30f;
    #pragma unroll
    for (int i = 0; i < 8; i++) amax = fmaxf(amax, av[i]);
    for (int m = 32; m >= 1; m >>= 1) amax = fmaxf(amax, __shfl_xor(amax, m, 64));
    if (lane == 0) sred[wid] = amax;
    __syncthreads();
    if (tid == 0)
        sred[4] = fmaxf(fmaxf(sred[0], sred[1]), fmaxf(sred[2], sred[3]));
    __syncthreads();
    const float invd = beta_pos / fmaxf(sred[4], 1e-6f);

    float sv[8], smax = -1e30f;
    #pragma unroll
    for (int i = 0; i < 8; i++) {
        sv[i] = ev[i] * (1.f + av[i] * invd);
        smax = fmaxf(smax, sv[i]);
    }
    for (int m = 32; m >= 1; m >>= 1) smax = fmaxf(smax, __shfl_xor(smax, m, 64));
    __syncthreads();
    if (lane == 0) sred[wid] = smax;
    __syncthreads();
    if (tid == 0)
        sred[5] = fmaxf(fmaxf(sred[0], sred[1]), fmaxf(sred[2], sred[3]));
    __syncthreads();
    const float smax_all = sred[5];

    float p[8], psum = 0.f;
    #pragma unroll
    for (int i = 0; i < 8; i++) { p[i] = __expf(sv[i] - smax_all); psum += p[i]; }
    for (int m = 32; m >= 1; m >>= 1) psum += __shfl_xor(psum, m, 64);
    __syncthreads();
    if (lane == 0) sred[wid] = psum;
    __syncthreads();
    if (tid == 0)
        sred[6] = sred[0] + sred[1] + sred[2] + sred[3];
    __syncthreads();
    const float invS = 1.f / sred[6];

    #pragma unroll
    for (int i = 0; i < 8; i++) al_s[tid * 8 + i] = p[i] * invS;
    __syncthreads();

    // write this block's alpha slice (coalesced, each t written by exactly one block)
    out_alpha[b * T_ + sl * 256 + tid] = al_s[sl * 256 + tid];

    // ---- context partial over rows t in [sl*256, sl*256+256) ----
    const int row = tid >> 5;      // 0..7
    const int c4  = tid & 31;      // float4 index within the 128-float row

    float c0 = 0.f, c1 = 0.f, c2 = 0.f, c3 = 0.f;
    const float* base = Hp + ((size_t)b * T_ + sl * 256) * H_ + c4 * 4;
    const float* al   = al_s + sl * 256;
    #pragma unroll 4
    for (int it = 0; it < 32; it++) {
        int t = it * 8 + row;
        float a = al[t];
        float4 v = *(const float4*)(base + (size_t)t * H_);
        c0 += a * v.x; c1 += a * v.y; c2 += a * v.z; c3 += a * v.w;
    }
    red[row * H_ + c4 * 4 + 0] = c0;
    red[row * H_ + c4 * 4 + 1] = c1;
    red[row * H_ + c4 * 4 + 2] = c2;
    red[row * H_ + c4 * 4 + 3] = c3;
    __syncthreads();
    if (tid < H_) {
        float s = 0.f;
        #pragma unroll
        for (int g = 0; g < 8; g++) s += red[g * H_ + tid];
        cpart[(b * 8 + sl) * H_ + tid] = s;
    }
}

__global__ __launch_bounds__(256) void ctx_reduce_kernel(
    const float* __restrict__ cpart, float* __restrict__ out_ctx)
{
    int i = blockIdx.x * 256 + threadIdx.x;   // i < B*H
    if (i < B_ * H_) {
        int b = i >> 7, h = i & 127;
        float s = 0.f;
        #pragma unroll
        for (int g = 0; g < 8; g++) s += cpart[(b * 8 + g) * H_ + h];
        out_ctx[i] = s;
    }
}

extern "C" void kernel_launch(void* const* d_in, const int* in_sizes, int n_in,
                              void* d_out, int out_size, void* d_ws, size_t ws_size,
                              hipStream_t stream) {
    const float* Hp   = (const float*)d_in[0];
    const float* Hd   = (const float*)d_in[1];
    const float* accw = (const float*)d_in[2];
    const float* Wh   = (const float*)d_in[3];
    const float* Wd   = (const float*)d_in[4];
    const float* Wa   = (const float*)d_in[5];
    const float* ba   = (const float*)d_in[6];
    const float* beta = (const float*)d_in[7];

    float* energy_ws = (float*)d_ws;                 // B*T fp32 = 1 MB
    float* cpart_ws  = energy_ws + B_ * T_;          // B*8*H fp32 = 512 KB

    float* out_ctx   = (float*)d_out;                // [B,H]
    float* out_alpha = out_ctx + B_ * H_;            // [B,T]

    const int ntiles = (B_ * T_) / 128;   // 2048 tiles of 128 rows
    energy_kernel<<<512, 512, 0, stream>>>(Hp, Hd, Wh, Wd, Wa, ba, energy_ws, ntiles);
    softmax_ctx_kernel<<<B_ * 8, 256, 0, stream>>>(Hp, accw, beta, energy_ws, out_alpha, cpart_ws);
    ctx_reduce_kernel<<<(B_ * H_ + 255) / 256, 256, 0, stream>>>(cpart_ws, out_ctx);
}

// Round 6
// 309.177 us; speedup vs baseline: 1.2938x; 1.0495x over previous
//
#include <hip/hip_runtime.h>

#define B_ 128
#define T_ 2048
#define H_ 128

typedef __attribute__((ext_vector_type(8))) short short8;
typedef __attribute__((ext_vector_type(4))) float f32x4;

__device__ __forceinline__ unsigned short f2b(float f) {
    unsigned int u = __float_as_uint(f);
    u += 0x7fffu + ((u >> 16) & 1u);   // RNE
    return (unsigned short)(u >> 16);
}
__device__ __forceinline__ short8 pack8(const float4 x, const float4 y) {
    short8 r;
    r[0] = (short)f2b(x.x); r[1] = (short)f2b(x.y);
    r[2] = (short)f2b(x.z); r[3] = (short)f2b(x.w);
    r[4] = (short)f2b(y.x); r[5] = (short)f2b(y.y);
    r[6] = (short)f2b(y.z); r[7] = (short)f2b(y.w);
    return r;
}
__device__ __forceinline__ float tanh_fast(float x) {
    x = fminf(fmaxf(x, -20.f), 20.f);
    float e = __expf(2.f * x);
    return (e - 1.f) / (e + 1.f);
}

// ---------------- Phase 0: amax[b] = max_t acc_w[b,t] ----------------
__global__ __launch_bounds__(256) void amax_kernel(
    const float* __restrict__ accw, float* __restrict__ amax_g)
{
    __shared__ float wred[4];
    const int b = blockIdx.x, tid = threadIdx.x;
    const float* p = accw + (size_t)b * T_ + tid * 8;
    float4 a0 = *(const float4*)p, a1 = *(const float4*)(p + 4);
    float m = fmaxf(fmaxf(fmaxf(a0.x, a0.y), fmaxf(a0.z, a0.w)),
                    fmaxf(fmaxf(a1.x, a1.y), fmaxf(a1.z, a1.w)));
    for (int d = 32; d >= 1; d >>= 1) m = fmaxf(m, __shfl_xor(m, d, 64));
    if ((tid & 63) == 0) wred[tid >> 6] = m;
    __syncthreads();
    if (tid == 0)
        amax_g[b] = fmaxf(fmaxf(wred[0], wred[1]), fmaxf(wred[2], wred[3]));
}

// ---------------- Phase 1 (fused): energy + online-softmax tile partials ----
// Per 128-row tile (16 tiles per b, never straddles b):
//   s_t = (W_a.tanh(W_h hp + W_d hd) + b_a) * (1 + betapos*acc_w/amax)
//   m_tile = max s_t; p_t = exp(s_t - m_tile); l_tile = sum p_t
//   ctxp[h] = sum_t p_t * Hp[t,h]   (Hp tile is L2-hot from the MFMA loads)
// MFMA main loop identical to v4 (depth-4 register pipeline + sched_barrier).
__global__ __launch_bounds__(512) void energy_kernel(
    const float* __restrict__ Hp,
    const float* __restrict__ Hd,
    const float* __restrict__ accw,
    const float* __restrict__ Wh,
    const float* __restrict__ Wd,
    const float* __restrict__ Wa,
    const float* __restrict__ ba_p,
    const float* __restrict__ beta_p,
    const float* __restrict__ amax_g,
    float* __restrict__ s_g,      // [B,T] scaled energies
    float* __restrict__ ml_g,     // [B,16,2] (m,l) per tile
    float* __restrict__ ctxp_g,   // [B,16,H] ctx partials
    int ntiles)
{
    __shared__ unsigned short Wpack[8 * 8 * 64 * 8];   // 64 KB [kt][nt][lane][8]
    __shared__ float Was[H_];
    __shared__ float e_s[128];
    __shared__ float s_s[128];
    __shared__ float p_s[128];
    __shared__ float red[16 * H_];   // 8 KB
    __shared__ float mld[2];

    const int tid = threadIdx.x;

    // stage W_h (kt 0..3) and W_d (kt 4..7) into read-order bf16 LDS
    for (int i = tid; i < (H_ * H_) / 4; i += 512) {
        int o  = i >> 5;
        int c4 = i & 31;
        float4 wh = *(const float4*)&Wh[o * H_ + c4 * 4];
        float4 wd = *(const float4*)&Wd[o * H_ + c4 * 4];
        uint2 ph, pdv;
        ph.x  = (unsigned)f2b(wh.x) | ((unsigned)f2b(wh.y) << 16);
        ph.y  = (unsigned)f2b(wh.z) | ((unsigned)f2b(wh.w) << 16);
        pdv.x = (unsigned)f2b(wd.x) | ((unsigned)f2b(wd.y) << 16);
        pdv.y = (unsigned)f2b(wd.z) | ((unsigned)f2b(wd.w) << 16);
        int nt   = o >> 4;
        int l15o = o & 15;
        int kth  = c4 >> 3;
        int lq   = (c4 >> 1) & 3;
        int half = (c4 & 1) * 4;
        int bh = ((kth * 8 + nt) * 64 + lq * 16 + l15o) * 8 + half;
        int bd = (((kth + 4) * 8 + nt) * 64 + lq * 16 + l15o) * 8 + half;
        *(uint2*)&Wpack[bh] = ph;
        *(uint2*)&Wpack[bd] = pdv;
    }
    if (tid < H_) Was[tid] = Wa[tid];
    __syncthreads();

    const float ba = ba_p[0];
    const float beta_pos = log1pf(__expf(beta_p[0]));

    const int wave = tid >> 6;
    const int lane = tid & 63;
    const int l15  = lane & 15;
    const int lq   = lane >> 4;

    const unsigned short* wb = Wpack + lane * 8;

    const size_t estep = (size_t)gridDim.x * 128 * H_;

    const int row0 = blockIdx.x * 128 + wave * 16;
    const float* pp = Hp + (size_t)(row0 + l15) * H_ + lq * 8;
    const float* pd = Hd + (size_t)(row0 + l15) * H_ + lq * 8;

    float4 abuf[8];
    #pragma unroll
    for (int c = 0; c < 4; c++) {
        abuf[2 * c]     = *(const float4*)(pp + c * 32);
        abuf[2 * c + 1] = *(const float4*)(pp + c * 32 + 4);
    }

    for (int tile = blockIdx.x; tile < ntiles; tile += gridDim.x) {
        __syncthreads();   // protect e_s/p_s/red reuse across tile iterations

        const int b  = tile >> 4;          // 16 tiles per b
        const int t0 = (tile & 15) * 128;
        const size_t adv = (tile + (int)gridDim.x < ntiles) ? estep : 0;
        const float* ppn = pp + adv;

        f32x4 acc[8];
        #pragma unroll
        for (int nt = 0; nt < 8; nt++) acc[nt] = (f32x4){0.f, 0.f, 0.f, 0.f};

        #pragma unroll
        for (int kt = 0; kt < 8; kt++) {
            const int sl = kt & 3;
            short8 af = pack8(abuf[2 * sl], abuf[2 * sl + 1]);
            const float* s = (kt < 4) ? (pd + kt * 32) : (ppn + (kt - 4) * 32);
            abuf[2 * sl]     = *(const float4*)s;
            abuf[2 * sl + 1] = *(const float4*)(s + 4);
            #pragma unroll
            for (int nt = 0; nt < 8; nt++) {
                short8 bf = *(const short8*)(wb + kt * 4096 + nt * 512);
                acc[nt] = __builtin_amdgcn_mfma_f32_16x16x32_bf16(af, bf, acc[nt], 0, 0, 0);
            }
            __builtin_amdgcn_sched_barrier(0);
        }
        pp = ppn;
        pd += adv;

        float ep[4] = {0.f, 0.f, 0.f, 0.f};
        #pragma unroll
        for (int nt = 0; nt < 8; nt++) {
            const float wa = Was[nt * 16 + l15];
            #pragma unroll
            for (int r = 0; r < 4; r++) ep[r] += tanh_fast(acc[nt][r]) * wa;
        }
        #pragma unroll
        for (int m = 1; m < 16; m <<= 1) {
            #pragma unroll
            for (int r = 0; r < 4; r++) ep[r] += __shfl_xor(ep[r], m, 64);
        }
        if (l15 == 0) {
            #pragma unroll
            for (int r = 0; r < 4; r++)
                e_s[wave * 16 + lq * 4 + r] = ep[r] + ba;
        }
        __syncthreads();

        // scale by acceleration term, store s
        if (tid < 128) {
            float a = accw[(size_t)b * T_ + t0 + tid];
            float invd = beta_pos / fmaxf(amax_g[b], 1e-6f);
            float s = e_s[tid] * (1.f + a * invd);
            s_s[tid] = s;
            s_g[(size_t)b * T_ + t0 + tid] = s;
        }
        __syncthreads();

        // tile max (wave 0)
        if (wave == 0) {
            float m = fmaxf(s_s[lane], s_s[lane + 64]);
            for (int d = 32; d >= 1; d >>= 1) m = fmaxf(m, __shfl_xor(m, d, 64));
            if (lane == 0) mld[0] = m;
        }
        __syncthreads();
        const float mt = mld[0];
        if (tid < 128) p_s[tid] = __expf(s_s[tid] - mt);
        __syncthreads();

        // tile sum (wave 0) -> write (m,l)
        if (wave == 0) {
            float l = p_s[lane] + p_s[lane + 64];
            for (int d = 32; d >= 1; d >>= 1) l += __shfl_xor(l, d, 64);
            if (lane == 0) {
                ml_g[(b * 16 + (tile & 15)) * 2 + 0] = mt;
                ml_g[(b * 16 + (tile & 15)) * 2 + 1] = l;
            }
        }

        // ctx partial: thread (g = tid>>5, c4 = tid&31) over rows g,g+16,...,g+112
        {
            const int g  = tid >> 5;
            const int c4 = tid & 31;
            const float* base = Hp + ((size_t)b * T_ + t0) * H_ + c4 * 4;
            float c0 = 0.f, c1 = 0.f, c2 = 0.f, c3 = 0.f;
            #pragma unroll
            for (int r = 0; r < 8; r++) {
                int t = r * 16 + g;
                float pv = p_s[t];
                float4 v = *(const float4*)(base + (size_t)t * H_);
                c0 += pv * v.x; c1 += pv * v.y; c2 += pv * v.z; c3 += pv * v.w;
            }
            red[g * H_ + c4 * 4 + 0] = c0;
            red[g * H_ + c4 * 4 + 1] = c1;
            red[g * H_ + c4 * 4 + 2] = c2;
            red[g * H_ + c4 * 4 + 3] = c3;
        }
        __syncthreads();
        if (tid < 128) {
            float s = 0.f;
            #pragma unroll
            for (int g = 0; g < 16; g++) s += red[g * H_ + tid];
            ctxp_g[((size_t)b * 16 + (tile & 15)) * H_ + tid] = s;
        }
    }
}

// ---------------- Phase 2: combine tile partials -> ctx, alpha ----------------
// grid = B; per b: M = max m_ti, L = sum exp(m_ti-M) l_ti;
// ctx = sum exp(m_ti-M)*ctxp_ti / L; alpha_t = exp(s_t - M)/L.
__global__ __launch_bounds__(256) void combine_kernel(
    const float* __restrict__ s_g,
    const float* __restrict__ ml_g,
    const float* __restrict__ ctxp_g,
    float* __restrict__ out_ctx,
    float* __restrict__ out_alpha)
{
    __shared__ float ml_s[32];
    const int b = blockIdx.x, tid = threadIdx.x;

    if (tid < 32) ml_s[tid] = ml_g[b * 32 + tid];
    __syncthreads();

    float M = -1e30f;
    #pragma unroll
    for (int i = 0; i < 16; i++) M = fmaxf(M, ml_s[2 * i]);
    float L = 0.f;
    #pragma unroll
    for (int i = 0; i < 16; i++) L += __expf(ml_s[2 * i] - M) * ml_s[2 * i + 1];
    const float invL = 1.f / L;

    if (tid < 128) {
        float s = 0.f;
        #pragma unroll
        for (int ti = 0; ti < 16; ti++)
            s += __expf(ml_s[2 * ti] - M) * ctxp_g[((size_t)b * 16 + ti) * H_ + tid];
        out_ctx[b * H_ + tid] = s * invL;
    }

    // alpha: 8 per thread, vectorized
    const float* ps = s_g + (size_t)b * T_ + tid * 8;
    float* pa = out_alpha + (size_t)b * T_ + tid * 8;
    float4 s0 = *(const float4*)ps, s1 = *(const float4*)(ps + 4);
    float4 a0, a1;
    a0.x = __expf(s0.x - M) * invL; a0.y = __expf(s0.y - M) * invL;
    a0.z = __expf(s0.z - M) * invL; a0.w = __expf(s0.w - M) * invL;
    a1.x = __expf(s1.x - M) * invL; a1.y = __expf(s1.y - M) * invL;
    a1.z = __expf(s1.z - M) * invL; a1.w = __expf(s1.w - M) * invL;
    *(float4*)pa = a0; *(float4*)(pa + 4) = a1;
}

extern "C" void kernel_launch(void* const* d_in, const int* in_sizes, int n_in,
                              void* d_out, int out_size, void* d_ws, size_t ws_size,
                              hipStream_t stream) {
    const float* Hp   = (const float*)d_in[0];
    const float* Hd   = (const float*)d_in[1];
    const float* accw = (const float*)d_in[2];
    const float* Wh   = (const float*)d_in[3];
    const float* Wd   = (const float*)d_in[4];
    const float* Wa   = (const float*)d_in[5];
    const float* ba   = (const float*)d_in[6];
    const float* beta = (const float*)d_in[7];

    float* s_ws    = (float*)d_ws;                     // B*T fp32 = 1 MB
    float* ctxp_ws = s_ws + B_ * T_;                   // B*16*H fp32 = 1 MB
    float* ml_ws   = ctxp_ws + B_ * 16 * H_;           // B*16*2 fp32 = 16 KB
    float* amax_ws = ml_ws + B_ * 16 * 2;              // B fp32

    float* out_ctx   = (float*)d_out;                  // [B,H]
    float* out_alpha = out_ctx + B_ * H_;              // [B,T]

    const int ntiles = (B_ * T_) / 128;   // 2048 tiles (16 per b)
    amax_kernel<<<B_, 256, 0, stream>>>(accw, amax_ws);
    energy_kernel<<<512, 512, 0, stream>>>(Hp, Hd, accw, Wh, Wd, Wa, ba, beta,
                                           amax_ws, s_ws, ml_ws, ctxp_ws, ntiles);
    combine_kernel<<<B_, 256, 0, stream>>>(s_ws, ml_ws, ctxp_ws, out_ctx, out_alpha);
}